// Round 1
// baseline (375.916 us; speedup 1.0000x reference)
//
#include <hip/hip_runtime.h>

constexpr int NH = 8;      // heads
constexpr int D  = 128;    // input dim
constexpr int DK = 16;     // key/val dim per head
constexpr int B  = 4;      // batch
constexpr int N  = 2048;   // graph nodes
constexpr float NORM = 0.25f;   // 1/sqrt(16)

// ---------------- kernel 1: QKV projection ----------------
// grid = B*N blocks, 128 threads. Output layout [H][B][N][DK].
__global__ __launch_bounds__(128) void qkv_kernel(
    const float* __restrict__ h, const float* __restrict__ Wq,
    const float* __restrict__ Wk, const float* __restrict__ Wv,
    float* __restrict__ Q, float* __restrict__ Ko, float* __restrict__ Vo)
{
    const int row = blockIdx.x;            // b*N + n
    const int t = threadIdx.x;             // 0..127
    __shared__ float hrow[D];
    hrow[t] = h[(size_t)row * D + t];
    __syncthreads();

    const int head = t >> 4;
    const int k    = t & 15;
    const float* wq = Wq + head * D * DK + k;
    const float* wk = Wk + head * D * DK + k;
    const float* wv = Wv + head * D * DK + k;
    float aq = 0.f, ak = 0.f, av = 0.f;
    #pragma unroll 8
    for (int d = 0; d < D; ++d) {
        const float x = hrow[d];
        aq = fmaf(x, wq[d * DK], aq);
        ak = fmaf(x, wk[d * DK], ak);
        av = fmaf(x, wv[d * DK], av);
    }
    const int b = row >> 11;               // row / N
    const int n = row & (N - 1);
    const size_t off = (((size_t)head * B + b) * N + n) * DK + k;
    Q[off] = aq; Ko[off] = ak; Vo[off] = av;
}

// ---------------- kernel 2: flash attention (fp32 VALU) ----------------
// One thread per q-row. grid = NH*B*(N/256), 256 threads.
// Online softmax with per-tile max; K/V tiles (32 rows) staged in LDS.
// Hd may alias Q: each thread reads its Q row into regs before any write.
constexpr int KT = 32;

__global__ __launch_bounds__(256) void attn_kernel(
    const float* __restrict__ Q, const float* __restrict__ K,
    const float* __restrict__ V, float* __restrict__ Hd)
{
    const int nqt = N / 256;               // 8
    const int hb  = blockIdx.x / nqt;      // head*B + b, 0..31
    const int qt  = blockIdx.x % nqt;
    const int t   = threadIdx.x;
    const size_t base = (size_t)hb * N * DK;
    const int qrow = qt * 256 + t;

    float q[DK];
    #pragma unroll
    for (int i = 0; i < DK; ++i) q[i] = Q[base + (size_t)qrow * DK + i] * NORM;

    float m = -3.0e38f, l = 0.f;
    float acc[DK];
    #pragma unroll
    for (int i = 0; i < DK; ++i) acc[i] = 0.f;

    __shared__ float Ks[KT * DK];
    __shared__ float Vs[KT * DK];

    for (int k0 = 0; k0 < N; k0 += KT) {
        __syncthreads();
        // KT*DK = 512 floats each; 256 threads -> 2 per thread, coalesced
        #pragma unroll
        for (int i = 0; i < 2; ++i) {
            const int idx = t + i * 256;
            Ks[idx] = K[base + (size_t)k0 * DK + idx];
            Vs[idx] = V[base + (size_t)k0 * DK + idx];
        }
        __syncthreads();

        float s[KT];
        #pragma unroll
        for (int kk = 0; kk < KT; ++kk) {
            float a = 0.f;
            #pragma unroll
            for (int i = 0; i < DK; ++i) a = fmaf(q[i], Ks[kk * DK + i], a);
            s[kk] = a;
        }
        float tm = s[0];
        #pragma unroll
        for (int kk = 1; kk < KT; ++kk) tm = fmaxf(tm, s[kk]);
        const float nm = fmaxf(m, tm);
        const float scale = __expf(m - nm);    // 0 on first tile (m=-3e38)
        l *= scale;
        #pragma unroll
        for (int i = 0; i < DK; ++i) acc[i] *= scale;
        #pragma unroll
        for (int kk = 0; kk < KT; ++kk) {
            const float p = __expf(s[kk] - nm);
            l += p;
            #pragma unroll
            for (int i = 0; i < DK; ++i) acc[i] = fmaf(p, Vs[kk * DK + i], acc[i]);
        }
        m = nm;
    }

    const float inv_l = 1.f / l;
    #pragma unroll
    for (int i = 0; i < DK; ++i)
        Hd[base + (size_t)qrow * DK + i] = acc[i] * inv_l;
}

// ---------------- kernel 3: output projection ----------------
// out[b,n,:] = concat_heads[b,n,:] @ Wout.reshape(128,128)
// grid = B*N blocks, 128 threads.
__global__ __launch_bounds__(128) void out_kernel(
    const float* __restrict__ Hd, const float* __restrict__ Wout,
    float* __restrict__ out)
{
    const int row = blockIdx.x;            // b*N + n
    const int t = threadIdx.x;             // 0..127 = output column e
    const int b = row >> 11;
    const int n = row & (N - 1);
    __shared__ float hr[D];
    {
        const int head = t >> 4, v = t & 15;
        hr[t] = Hd[(((size_t)head * B + b) * N + n) * DK + v];
    }
    __syncthreads();
    float a = 0.f;
    #pragma unroll 8
    for (int j = 0; j < D; ++j)
        a = fmaf(hr[j], Wout[j * D + t], a);
    out[(size_t)row * D + t] = a;
}

extern "C" void kernel_launch(void* const* d_in, const int* in_sizes, int n_in,
                              void* d_out, int out_size, void* d_ws, size_t ws_size,
                              hipStream_t stream) {
    const float* h  = (const float*)d_in[0];
    const float* Wq = (const float*)d_in[1];
    const float* Wk = (const float*)d_in[2];
    const float* Wv = (const float*)d_in[3];
    const float* Wo = (const float*)d_in[4];
    float* out = (float*)d_out;

    const size_t per = (size_t)NH * B * N * DK;   // 1,048,576 floats = 4 MB
    float* Q = (float*)d_ws;                      // heads alias Q after attn
    float* K = Q + per;
    float* V = K + per;                           // total ws use: 12 MB

    qkv_kernel<<<B * N, 128, 0, stream>>>(h, Wq, Wk, Wv, Q, K, V);
    attn_kernel<<<NH * B * (N / 256), 256, 0, stream>>>(Q, K, V, Q);
    out_kernel<<<B * N, 128, 0, stream>>>(Q, Wo, out);
}

// Round 2
// 212.560 us; speedup vs baseline: 1.7685x; 1.7685x over previous
//
#include <hip/hip_runtime.h>

constexpr int NH = 8;      // heads
constexpr int D  = 128;    // input dim
constexpr int DK = 16;     // key/val dim per head
constexpr int B  = 4;      // batch
constexpr int N  = 2048;   // graph nodes
constexpr float NORM = 0.25f;   // 1/sqrt(16)

// ---------------- kernel 1: QKV projection ----------------
// grid = B*N blocks, 128 threads. Output layout [H][B][N][DK].
__global__ __launch_bounds__(128) void qkv_kernel(
    const float* __restrict__ h, const float* __restrict__ Wq,
    const float* __restrict__ Wk, const float* __restrict__ Wv,
    float* __restrict__ Q, float* __restrict__ Ko, float* __restrict__ Vo)
{
    const int row = blockIdx.x;            // b*N + n
    const int t = threadIdx.x;             // 0..127
    __shared__ float hrow[D];
    hrow[t] = h[(size_t)row * D + t];
    __syncthreads();

    const int head = t >> 4;
    const int k    = t & 15;
    const float* wq = Wq + head * D * DK + k;
    const float* wk = Wk + head * D * DK + k;
    const float* wv = Wv + head * D * DK + k;
    float aq = 0.f, ak = 0.f, av = 0.f;
    #pragma unroll 8
    for (int d = 0; d < D; ++d) {
        const float x = hrow[d];
        aq = fmaf(x, wq[d * DK], aq);
        ak = fmaf(x, wk[d * DK], ak);
        av = fmaf(x, wv[d * DK], av);
    }
    const int b = row >> 11;               // row / N
    const int n = row & (N - 1);
    const size_t off = (((size_t)head * B + b) * N + n) * DK + k;
    Q[off] = aq; Ko[off] = ak; Vo[off] = av;
}

// ---------------- kernel 2: flash attention (fp32 VALU, 4 lanes per q-row) ---
// Each q-row is handled by 4 consecutive lanes; lane c processes keys with
// key%4==c (online softmax per lane), then a 2-step shfl_xor butterfly merges
// (m, l, acc[16]) within the 4-lane group. 4x the wave count of the v1 kernel:
// grid = 32 hb * 32 qtiles = 1024 blocks * 4 waves = 16 waves/CU.
constexpr int QT    = 64;   // q rows per block
constexpr int KTILE = 64;   // keys staged in LDS per tile

__global__ __launch_bounds__(256) void attn_kernel(
    const float* __restrict__ Q, const float* __restrict__ K,
    const float* __restrict__ V, float* __restrict__ Hd)
{
    const int nqt = N / QT;                // 32
    const int hb  = blockIdx.x / nqt;      // head*B + b, 0..31
    const int qt  = blockIdx.x % nqt;
    const int t   = threadIdx.x;
    const int c   = t & 3;                 // lane within 4-group
    const int ql  = t >> 2;                // 0..63 local q row
    const size_t base = (size_t)hb * N * DK;
    const int qrow = qt * QT + ql;

    float q[DK];
    #pragma unroll
    for (int i = 0; i < DK; ++i) q[i] = Q[base + (size_t)qrow * DK + i] * NORM;

    float m = -3.0e38f, l = 0.f;
    float acc[DK];
    #pragma unroll
    for (int i = 0; i < DK; ++i) acc[i] = 0.f;

    __shared__ float Ks[KTILE * DK];       // 4 KB
    __shared__ float Vs[KTILE * DK];       // 4 KB

    for (int k0 = 0; k0 < N; k0 += KTILE) {
        __syncthreads();
        // KTILE*DK = 1024 floats = 256 float4 each; one float4 per thread
        ((float4*)Ks)[t] = ((const float4*)(K + base + (size_t)k0 * DK))[t];
        ((float4*)Vs)[t] = ((const float4*)(V + base + (size_t)k0 * DK))[t];
        __syncthreads();

        // this lane's 16 keys: key = 4*i + c
        float s[16];
        #pragma unroll
        for (int i = 0; i < 16; ++i) {
            const int key = (i << 2) | c;
            float a = 0.f;
            #pragma unroll
            for (int d = 0; d < DK; ++d) a = fmaf(q[d], Ks[key * DK + d], a);
            s[i] = a;
        }
        float tm = s[0];
        #pragma unroll
        for (int i = 1; i < 16; ++i) tm = fmaxf(tm, s[i]);
        const float nm = fmaxf(m, tm);
        const float scale = __expf(m - nm);    // 0 on first tile
        l *= scale;
        #pragma unroll
        for (int d = 0; d < DK; ++d) acc[d] *= scale;
        #pragma unroll
        for (int i = 0; i < 16; ++i) {
            const int key = (i << 2) | c;
            const float p = __expf(s[i] - nm);
            l += p;
            #pragma unroll
            for (int d = 0; d < DK; ++d) acc[d] = fmaf(p, Vs[key * DK + d], acc[d]);
        }
        m = nm;
    }

    // butterfly merge of (m, l, acc) across the 4-lane group
    #pragma unroll
    for (int off = 1; off <= 2; off <<= 1) {
        const float mo = __shfl_xor(m, off, 64);
        const float lo = __shfl_xor(l, off, 64);
        const float nm = fmaxf(m, mo);
        const float s1 = __expf(m - nm);
        const float s2 = __expf(mo - nm);
        l = l * s1 + lo * s2;
        #pragma unroll
        for (int d = 0; d < DK; ++d) {
            const float ao = __shfl_xor(acc[d], off, 64);
            acc[d] = acc[d] * s1 + ao * s2;
        }
        m = nm;
    }

    const float inv_l = 1.f / l;
    // lane c writes floats [4c, 4c+4) of the row — static register indexing
    float4 o;
    o.x = (c == 0 ? acc[0] : c == 1 ? acc[4] : c == 2 ? acc[8]  : acc[12]) * inv_l;
    o.y = (c == 0 ? acc[1] : c == 1 ? acc[5] : c == 2 ? acc[9]  : acc[13]) * inv_l;
    o.z = (c == 0 ? acc[2] : c == 1 ? acc[6] : c == 2 ? acc[10] : acc[14]) * inv_l;
    o.w = (c == 0 ? acc[3] : c == 1 ? acc[7] : c == 2 ? acc[11] : acc[15]) * inv_l;
    ((float4*)(Hd + base + (size_t)qrow * DK))[c] = o;
}

// ---------------- kernel 3: output projection ----------------
// out[b,n,:] = concat_heads[b,n,:] @ Wout.reshape(128,128)
__global__ __launch_bounds__(128) void out_kernel(
    const float* __restrict__ Hd, const float* __restrict__ Wout,
    float* __restrict__ out)
{
    const int row = blockIdx.x;            // b*N + n
    const int t = threadIdx.x;             // 0..127 = output column e
    const int b = row >> 11;
    const int n = row & (N - 1);
    __shared__ float hr[D];
    {
        const int head = t >> 4, v = t & 15;
        hr[t] = Hd[(((size_t)head * B + b) * N + n) * DK + v];
    }
    __syncthreads();
    float a = 0.f;
    #pragma unroll 8
    for (int j = 0; j < D; ++j)
        a = fmaf(hr[j], Wout[j * D + t], a);
    out[(size_t)row * D + t] = a;
}

extern "C" void kernel_launch(void* const* d_in, const int* in_sizes, int n_in,
                              void* d_out, int out_size, void* d_ws, size_t ws_size,
                              hipStream_t stream) {
    const float* h  = (const float*)d_in[0];
    const float* Wq = (const float*)d_in[1];
    const float* Wk = (const float*)d_in[2];
    const float* Wv = (const float*)d_in[3];
    const float* Wo = (const float*)d_in[4];
    float* out = (float*)d_out;

    const size_t per = (size_t)NH * B * N * DK;   // 1,048,576 floats = 4 MB
    float* Q = (float*)d_ws;                      // heads alias Q after attn
    float* K = Q + per;
    float* V = K + per;                           // total ws use: 12 MB

    qkv_kernel<<<B * N, 128, 0, stream>>>(h, Wq, Wk, Wv, Q, K, V);
    attn_kernel<<<NH * B * (N / QT), 256, 0, stream>>>(Q, K, V, Q);
    out_kernel<<<B * N, 128, 0, stream>>>(Q, Wo, out);
}

// Round 3
// 122.742 us; speedup vs baseline: 3.0627x; 1.7318x over previous
//
#include <hip/hip_runtime.h>

typedef __attribute__((ext_vector_type(4))) float f32x4;
typedef __attribute__((ext_vector_type(8))) short bf16x8;

constexpr int NH = 8;      // heads
constexpr int D  = 128;    // input dim
constexpr int DK = 16;     // key/val dim per head
constexpr int B  = 4;      // batch
constexpr int N  = 2048;   // graph nodes
constexpr float NORM = 0.25f;   // 1/sqrt(16)

__device__ __forceinline__ unsigned short f2bf(float f) {
    union { float f; unsigned u; } v; v.f = f;
    unsigned r = (v.u + 0x7fffu + ((v.u >> 16) & 1u)) >> 16;   // RNE
    return (unsigned short)r;
}
__device__ __forceinline__ float bf2f(unsigned short h) {
    union { unsigned u; float f; } v; v.u = ((unsigned)h) << 16;
    return v.f;
}

// ---------------- kernel 1: QKV projection (fp32 VALU, 8 rows/block) --------
constexpr int QKV_ROWS = 8;
__global__ __launch_bounds__(128) void qkv_kernel(
    const float* __restrict__ h, const float* __restrict__ Wq,
    const float* __restrict__ Wk, const float* __restrict__ Wv,
    float* __restrict__ Q, float* __restrict__ Ko, float* __restrict__ Vo)
{
    const int row0 = blockIdx.x * QKV_ROWS;
    const int b = row0 >> 11, n0 = row0 & (N - 1);
    const int t = threadIdx.x;
    __shared__ float hs[QKV_ROWS][D];
    #pragma unroll
    for (int i = 0; i < 2; ++i) {
        const int f4 = t + i * 128;             // 256 float4 = 8x128 floats
        const int r = f4 >> 5, c4 = (f4 & 31) * 4;
        *(float4*)&hs[r][c4] = *(const float4*)&h[(size_t)(row0 + r) * D + c4];
    }
    __syncthreads();
    const int head = t >> 4, kk = t & 15;
    const float* wq = Wq + head * D * DK + kk;
    const float* wk = Wk + head * D * DK + kk;
    const float* wv = Wv + head * D * DK + kk;
    float aq[QKV_ROWS] = {}, ak[QKV_ROWS] = {}, av[QKV_ROWS] = {};
    for (int d0 = 0; d0 < D; d0 += 4) {
        float wqv[4], wkv[4], wvv[4];
        #pragma unroll
        for (int dd = 0; dd < 4; ++dd) {
            wqv[dd] = wq[(d0 + dd) * DK];
            wkv[dd] = wk[(d0 + dd) * DK];
            wvv[dd] = wv[(d0 + dd) * DK];
        }
        #pragma unroll
        for (int r = 0; r < QKV_ROWS; ++r) {
            float4 hv = *(const float4*)&hs[r][d0];
            const float* hp = (const float*)&hv;
            #pragma unroll
            for (int dd = 0; dd < 4; ++dd) {
                aq[r] = fmaf(hp[dd], wqv[dd], aq[r]);
                ak[r] = fmaf(hp[dd], wkv[dd], ak[r]);
                av[r] = fmaf(hp[dd], wvv[dd], av[r]);
            }
        }
    }
    #pragma unroll
    for (int r = 0; r < QKV_ROWS; ++r) {
        const size_t off = (((size_t)head * B + b) * N + (n0 + r)) * DK + kk;
        Q[off] = aq[r]; Ko[off] = ak[r]; Vo[off] = av[r];
    }
}

// ---------------- kernel 2: flash attention via MFMA 16x16x32 bf16 ----------
// Per block: 4 waves x 16 q-rows = 64 q rows of one (head,b). KTILE=64 keys.
// QK^T: S^T = mfma(A=K[16k x 32(dk hi|lo)], B=[Qhi|Qlo]) + mfma(A, [Qlo|Qhi])
//   -> exact split-bf16 product; acc: col=q=lane&15, row=key=(lane>>4)*4+reg.
// softmax: in-lane over 8 regs + shfl_xor(16,32). P->bf16 via per-wave LDS
// roundtrip into B-frag order. PV: O^T = mfma(A=V^T (LDS-transposed), B=P^T).
constexpr int KTILE = 64;
constexpr int QT    = 64;

__global__ __launch_bounds__(256) void attn_kernel(
    const float* __restrict__ Q, const float* __restrict__ K,
    const float* __restrict__ V, float* __restrict__ Hd)
{
    const int nqt = N / QT;                 // 32
    const int hb = blockIdx.x / nqt;
    const int qt = blockIdx.x % nqt;
    const int t = threadIdx.x;
    const int w = t >> 6;                   // wave 0..3
    const int l = t & 63;
    const int q16 = l & 15;                 // q col (and dv row for V-frag)
    const int g = l >> 4;                   // lane group 0..3
    const size_t base = (size_t)hb * N * DK;

    __shared__ unsigned short Kf[4][64][8];   // frag-ordered K hi|lo, 4 subtiles
    __shared__ unsigned short Vt2[16][80];    // V^T [dv][key], padded stride 80
    __shared__ unsigned short Pl[4][16][32];  // per-wave P frag buffer

    // ---- hoisted Q fragments (hi/lo split, packed into K=32 halves) ----
    const int qrow = qt * QT + w * 16 + q16;
    bf16x8 qhi, qlo;
    {
        const float* qp = Q + base + (size_t)qrow * DK + (g & 1) * 8;
        #pragma unroll
        for (int j = 0; j < 8; ++j) {
            const float x = qp[j] * NORM;
            const unsigned short h = f2bf(x);
            qhi[j] = (short)h;
            qlo[j] = (short)f2bf(x - bf2f(h));
        }
    }
    const bf16x8 qf1 = (g < 2) ? qhi : qlo;   // [Qhi|Qlo] along K=32
    const bf16x8 qf2 = (g < 2) ? qlo : qhi;   // [Qlo|Qhi]

    f32x4 oacc = {0.f, 0.f, 0.f, 0.f};
    float m = -3.0e38f, lsum = 0.f;

    const int skey = t >> 2, sdg = t & 3, sdk0 = sdg * 4;   // staging roles

    for (int k0 = 0; k0 < N; k0 += KTILE) {
        __syncthreads();
        {   // stage 64 keys: K as hi/lo frag-ordered, V transposed bf16
            const float* kp = K + base + (size_t)(k0 + skey) * DK + sdk0;
            const float* vp = V + base + (size_t)(k0 + skey) * DK + sdk0;
            float4 kv = *(const float4*)kp;
            float4 vv = *(const float4*)vp;
            const float* kpp = (const float*)&kv;
            const float* vpp = (const float*)&vv;
            unsigned short kh[4], kl[4];
            #pragma unroll
            for (int i = 0; i < 4; ++i) {
                kh[i] = f2bf(kpp[i]);
                kl[i] = f2bf(kpp[i] - bf2f(kh[i]));
            }
            const int s = skey >> 4, k15 = skey & 15;
            const int jo = sdk0 & 7, gsel = sdk0 >> 3;
            unsigned short* hd = &Kf[s][k15 | (gsel << 4)][jo];
            hd[0] = kh[0]; hd[1] = kh[1]; hd[2] = kh[2]; hd[3] = kh[3];
            unsigned short* ld = &Kf[s][k15 | ((gsel + 2) << 4)][jo];
            ld[0] = kl[0]; ld[1] = kl[1]; ld[2] = kl[2]; ld[3] = kl[3];
            #pragma unroll
            for (int i = 0; i < 4; ++i) Vt2[sdk0 + i][skey] = f2bf(vpp[i]);
        }
        __syncthreads();

        #pragma unroll
        for (int s2 = 0; s2 < 2; ++s2) {        // two 32-key steps
            const f32x4 zero = {0.f, 0.f, 0.f, 0.f};
            bf16x8 kf0 = *(const bf16x8*)&Kf[2 * s2][l][0];
            f32x4 a0 = __builtin_amdgcn_mfma_f32_16x16x32_bf16(kf0, qf1, zero, 0, 0, 0);
            a0 = __builtin_amdgcn_mfma_f32_16x16x32_bf16(kf0, qf2, a0, 0, 0, 0);
            bf16x8 kf1 = *(const bf16x8*)&Kf[2 * s2 + 1][l][0];
            f32x4 a1 = __builtin_amdgcn_mfma_f32_16x16x32_bf16(kf1, qf1, zero, 0, 0, 0);
            a1 = __builtin_amdgcn_mfma_f32_16x16x32_bf16(kf1, qf2, a1, 0, 0, 0);

            // online softmax over this step's 32 keys (8 in-lane + xor16/32)
            float tm = fmaxf(fmaxf(fmaxf(a0[0], a0[1]), fmaxf(a0[2], a0[3])),
                             fmaxf(fmaxf(a1[0], a1[1]), fmaxf(a1[2], a1[3])));
            tm = fmaxf(tm, __shfl_xor(tm, 16));
            tm = fmaxf(tm, __shfl_xor(tm, 32));
            const float nm = fmaxf(m, tm);
            const float sc = __expf(m - nm);
            float p[8];
            #pragma unroll
            for (int i = 0; i < 4; ++i) p[i] = __expf(a0[i] - nm);
            #pragma unroll
            for (int i = 0; i < 4; ++i) p[4 + i] = __expf(a1[i] - nm);
            float ts = ((p[0] + p[1]) + (p[2] + p[3])) + ((p[4] + p[5]) + (p[6] + p[7]));
            ts += __shfl_xor(ts, 16);
            ts += __shfl_xor(ts, 32);
            lsum = lsum * sc + ts;
            m = nm;
            oacc *= sc;

            // P (fp32 acc layout) -> bf16 B-frag via per-wave LDS roundtrip
            unsigned short* pw0 = &Pl[w][q16][g * 4];
            pw0[0] = f2bf(p[0]); pw0[1] = f2bf(p[1]);
            pw0[2] = f2bf(p[2]); pw0[3] = f2bf(p[3]);
            unsigned short* pw1 = &Pl[w][q16][16 + g * 4];
            pw1[0] = f2bf(p[4]); pw1[1] = f2bf(p[5]);
            pw1[2] = f2bf(p[6]); pw1[3] = f2bf(p[7]);
            bf16x8 pf = *(const bf16x8*)&Pl[w][q16][g * 8];
            bf16x8 vf = *(const bf16x8*)&Vt2[q16][s2 * 32 + g * 8];
            oacc = __builtin_amdgcn_mfma_f32_16x16x32_bf16(vf, pf, oacc, 0, 0, 0);
        }
    }

    // epilogue: lane holds O^T[dv=g*4+r][q=q16]; write float4 row segment
    const float invl = 1.f / lsum;
    float4 o;
    o.x = oacc[0] * invl; o.y = oacc[1] * invl;
    o.z = oacc[2] * invl; o.w = oacc[3] * invl;
    *(float4*)(Hd + base + (size_t)qrow * DK + g * 4) = o;
}

// ---------------- kernel 3: output projection (fp32 VALU, 8 rows/block) -----
constexpr int OUT_ROWS = 8;
__global__ __launch_bounds__(128) void out_kernel(
    const float* __restrict__ Hd, const float* __restrict__ Wout,
    float* __restrict__ out)
{
    const int row0 = blockIdx.x * OUT_ROWS;
    const int b = row0 >> 11, n0 = row0 & (N - 1);
    const int t = threadIdx.x;
    __shared__ float hr[OUT_ROWS][D];
    #pragma unroll
    for (int i = 0; i < 2; ++i) {
        const int f4 = t + i * 128;
        const int r = f4 >> 5, j4 = (f4 & 31) * 4;
        const int head = j4 >> 4, v0 = j4 & 15;
        *(float4*)&hr[r][j4] =
            *(const float4*)&Hd[(((size_t)head * B + b) * N + (n0 + r)) * DK + v0];
    }
    __syncthreads();
    float acc[OUT_ROWS] = {};
    for (int d0 = 0; d0 < D; d0 += 4) {
        float wv[4];
        #pragma unroll
        for (int dd = 0; dd < 4; ++dd) wv[dd] = Wout[(size_t)(d0 + dd) * D + t];
        #pragma unroll
        for (int r = 0; r < OUT_ROWS; ++r) {
            float4 hv = *(const float4*)&hr[r][d0];
            const float* hp = (const float*)&hv;
            #pragma unroll
            for (int dd = 0; dd < 4; ++dd) acc[r] = fmaf(hp[dd], wv[dd], acc[r]);
        }
    }
    #pragma unroll
    for (int r = 0; r < OUT_ROWS; ++r)
        out[(size_t)(row0 + r) * D + t] = acc[r];
}

extern "C" void kernel_launch(void* const* d_in, const int* in_sizes, int n_in,
                              void* d_out, int out_size, void* d_ws, size_t ws_size,
                              hipStream_t stream) {
    const float* h  = (const float*)d_in[0];
    const float* Wq = (const float*)d_in[1];
    const float* Wk = (const float*)d_in[2];
    const float* Wv = (const float*)d_in[3];
    const float* Wo = (const float*)d_in[4];
    float* out = (float*)d_out;

    const size_t per = (size_t)NH * B * N * DK;   // 4 MB each
    float* Q = (float*)d_ws;                      // heads alias Q after attn
    float* K = Q + per;
    float* V = K + per;

    qkv_kernel<<<B * N / QKV_ROWS, 128, 0, stream>>>(h, Wq, Wk, Wv, Q, K, V);
    attn_kernel<<<NH * B * (N / QT), 256, 0, stream>>>(Q, K, V, Q);
    out_kernel<<<B * N / OUT_ROWS, 128, 0, stream>>>(Q, Wo, out);
}

// Round 4
// 98.235 us; speedup vs baseline: 3.8267x; 1.2495x over previous
//
#include <hip/hip_runtime.h>

typedef __attribute__((ext_vector_type(4))) float f32x4;
typedef __attribute__((ext_vector_type(8))) short bf16x8;

constexpr int NH = 8, D = 128, DK = 16, B = 4, N = 2048;
constexpr int NTILES = N / 64;          // 32 key-tiles of 64
constexpr int TILE_SHORTS = 3072;       // 6144 B: 4096 B Khl frag + 2048 B Vt swz
constexpr float QSCALE = 0.36067376022224085f;   // 0.25 * log2(e)

__device__ __forceinline__ unsigned short f2bf(float f) {
    union { float f; unsigned u; } v; v.f = f;
    return (unsigned short)((v.u + 0x7fffu + ((v.u >> 16) & 1u)) >> 16);
}
__device__ __forceinline__ float bf2f(unsigned short h) {
    union { unsigned u; float f; } v; v.u = ((unsigned)h) << 16; return v.f;
}
__device__ __forceinline__ unsigned pack2(float a, float b) {   // bf16 trunc pair
    union { float f; unsigned u; } x, y; x.f = a; y.f = b;
    return (x.u >> 16) | (y.u & 0xFFFF0000u);
}

// ---------------- kernel 1: QKV projection + K/V pre-conversion -------------
// Q fp32 [hb][n][16]. KV per (hb,tile) 6KB record:
//   Khl frag-order (key-permuted rows, hi then lo gsel) bytes [0,4096)
//   V^T bf16 XOR-swizzled (16B granules) bytes [4096,6144)
constexpr int QKV_ROWS = 8;
__global__ __launch_bounds__(128) void qkv_kernel(
    const float* __restrict__ h, const float* __restrict__ Wq,
    const float* __restrict__ Wk, const float* __restrict__ Wv,
    float* __restrict__ Q, unsigned short* __restrict__ KV)
{
    const int row0 = blockIdx.x * QKV_ROWS;
    const int b = row0 >> 11, n0 = row0 & (N - 1);
    const int t = threadIdx.x;
    __shared__ float hs[QKV_ROWS][D];
    #pragma unroll
    for (int i = 0; i < 2; ++i) {
        const int f4 = t + i * 128;
        const int r = f4 >> 5, c4 = (f4 & 31) * 4;
        *(float4*)&hs[r][c4] = *(const float4*)&h[(size_t)(row0 + r) * D + c4];
    }
    __syncthreads();
    const int head = t >> 4, kk = t & 15;
    const float* wq = Wq + head * D * DK + kk;
    const float* wk = Wk + head * D * DK + kk;
    const float* wv = Wv + head * D * DK + kk;
    float aq[QKV_ROWS] = {}, ak[QKV_ROWS] = {}, av[QKV_ROWS] = {};
    for (int d0 = 0; d0 < D; d0 += 4) {
        float wqv[4], wkv[4], wvv[4];
        #pragma unroll
        for (int dd = 0; dd < 4; ++dd) {
            wqv[dd] = wq[(d0 + dd) * DK];
            wkv[dd] = wk[(d0 + dd) * DK];
            wvv[dd] = wv[(d0 + dd) * DK];
        }
        #pragma unroll
        for (int r = 0; r < QKV_ROWS; ++r) {
            float4 hv = *(const float4*)&hs[r][d0];
            const float* hp = (const float*)&hv;
            #pragma unroll
            for (int dd = 0; dd < 4; ++dd) {
                aq[r] = fmaf(hp[dd], wqv[dd], aq[r]);
                ak[r] = fmaf(hp[dd], wkv[dd], ak[r]);
                av[r] = fmaf(hp[dd], wvv[dd], av[r]);
            }
        }
    }
    const int hb = head * B + b;
    unsigned short* kvb = KV + (size_t)hb * NTILES * TILE_SHORTS;
    const int j = kk & 7, gs = kk >> 3;
    #pragma unroll
    for (int r = 0; r < QKV_ROWS; ++r) {
        const int key = n0 + r;
        Q[((size_t)hb * N + key) * DK + kk] = aq[r];
        unsigned short* tb = kvb + (size_t)(key >> 6) * TILE_SHORTS;
        const int rl = key & 63;
        // K: permuted frag rows so QK acc regs == PV B-frag order
        const int grp = rl >> 5, kap = rl & 31;
        const int sub = 2 * grp + ((kap >> 2) & 1);
        const int row16 = 4 * (kap >> 3) + (kap & 3);
        const unsigned short khi = f2bf(ak[r]);
        const unsigned short klo = f2bf(ak[r] - bf2f(khi));
        tb[sub * 512 + (row16 + 16 * gs) * 8 + j] = khi;
        tb[sub * 512 + (row16 + 16 * (2 + gs)) * 8 + j] = klo;
        // V^T swizzled: dv=kk, 16B-granule idx (key>>3) ^ (dv&7)
        tb[2048 + kk * 64 + (((rl >> 3) ^ (kk & 7)) * 8) + (rl & 7)] = f2bf(av[r]);
    }
}

// ---------------- kernel 2: flash attention, all-MFMA, in-register P --------
// 4 waves x 16 q-rows. Per 64-key tile: 4 Kf b128 + 2 Vt b128 reads,
// 8 QK mfma (hi/lo exact) + 1 softmax update + 2 PV mfma. Double-buffered
// reg-staged LDS (6KB/buf), loads issued before compute (T14).
__global__ __launch_bounds__(256) void attn_kernel(
    const float* __restrict__ Q, const unsigned short* __restrict__ KV,
    float* __restrict__ Hd)
{
    const int bid = blockIdx.x;
    // XCD swizzle: 4 consecutive hb per XCD -> KV record stays L2-resident
    const int hb = (bid & 7) * 4 + ((bid >> 3) >> 5);
    const int qt = (bid >> 3) & 31;
    const int t = threadIdx.x, w = t >> 6, l = t & 63;
    const int q16 = l & 15, g = l >> 4;
    const size_t qbase = (size_t)hb * N * DK;
    const char* kvb = (const char*)(KV + (size_t)hb * NTILES * TILE_SHORTS);

    __shared__ unsigned short smem[2][TILE_SHORTS];

    const int qrow = qt * 64 + w * 16 + q16;
    bf16x8 qhi, qlo;
    {
        const float* qp = Q + qbase + (size_t)qrow * DK + (g & 1) * 8;
        float4 qa = *(const float4*)qp, qb = *(const float4*)(qp + 4);
        const float* qv = (const float*)&qa;
        #pragma unroll
        for (int i = 0; i < 8; ++i) {
            const float x = (i < 4 ? qv[i] : ((const float*)&qb)[i - 4]) * QSCALE;
            const unsigned short hi = f2bf(x);
            qhi[i] = (short)hi;
            qlo[i] = (short)f2bf(x - bf2f(hi));
        }
    }
    const bf16x8 qf1 = (g < 2) ? qhi : qlo;
    const bf16x8 qf2 = (g < 2) ? qlo : qhi;

    f32x4 oacc = {0.f, 0.f, 0.f, 0.f};
    float m = -3.0e38f, lsum = 0.f;

    // prologue: stage tile 0
    uint4 kreg = *(const uint4*)(kvb + t * 16);
    uint2 vreg = *(const uint2*)(kvb + 4096 + t * 8);
    *(uint4*)((char*)&smem[0][0] + t * 16) = kreg;
    *(uint2*)((char*)&smem[0][0] + 4096 + t * 8) = vreg;

    int cur = 0;
    for (int tile = 0; tile < NTILES; ++tile) {
        __syncthreads();
        if (tile + 1 < NTILES) {            // issue next-tile loads early
            const char* gt = kvb + (size_t)(tile + 1) * 6144;
            kreg = *(const uint4*)(gt + t * 16);
            vreg = *(const uint2*)(gt + 4096 + t * 8);
        }
        const char* buf = (const char*)&smem[cur][0];
        bf16x8 kf0 = *(const bf16x8*)(buf + 0 * 1024 + l * 16);
        bf16x8 kf1 = *(const bf16x8*)(buf + 1 * 1024 + l * 16);
        bf16x8 kf2 = *(const bf16x8*)(buf + 2 * 1024 + l * 16);
        bf16x8 kf3 = *(const bf16x8*)(buf + 3 * 1024 + l * 16);
        bf16x8 vf0 = *(const bf16x8*)(buf + 4096 + q16 * 128 + ((g) ^ (q16 & 7)) * 16);
        bf16x8 vf1 = *(const bf16x8*)(buf + 4096 + q16 * 128 + ((4 + g) ^ (q16 & 7)) * 16);

        const f32x4 z = {0.f, 0.f, 0.f, 0.f};
        f32x4 a0 = __builtin_amdgcn_mfma_f32_16x16x32_bf16(kf0, qf1, z, 0, 0, 0);
        a0 = __builtin_amdgcn_mfma_f32_16x16x32_bf16(kf0, qf2, a0, 0, 0, 0);
        f32x4 a1 = __builtin_amdgcn_mfma_f32_16x16x32_bf16(kf1, qf1, z, 0, 0, 0);
        a1 = __builtin_amdgcn_mfma_f32_16x16x32_bf16(kf1, qf2, a1, 0, 0, 0);
        f32x4 a2 = __builtin_amdgcn_mfma_f32_16x16x32_bf16(kf2, qf1, z, 0, 0, 0);
        a2 = __builtin_amdgcn_mfma_f32_16x16x32_bf16(kf2, qf2, a2, 0, 0, 0);
        f32x4 a3 = __builtin_amdgcn_mfma_f32_16x16x32_bf16(kf3, qf1, z, 0, 0, 0);
        a3 = __builtin_amdgcn_mfma_f32_16x16x32_bf16(kf3, qf2, a3, 0, 0, 0);

        // one online-softmax update over all 64 keys (base-2 domain)
        float t0 = fmaxf(fmaxf(a0[0], a0[1]), fmaxf(a0[2], a0[3]));
        float t1 = fmaxf(fmaxf(a1[0], a1[1]), fmaxf(a1[2], a1[3]));
        float t2 = fmaxf(fmaxf(a2[0], a2[1]), fmaxf(a2[2], a2[3]));
        float t3 = fmaxf(fmaxf(a3[0], a3[1]), fmaxf(a3[2], a3[3]));
        float tm = fmaxf(fmaxf(t0, t1), fmaxf(t2, t3));
        tm = fmaxf(tm, __shfl_xor(tm, 16));
        tm = fmaxf(tm, __shfl_xor(tm, 32));
        const float nm = fmaxf(m, tm);
        const float sc = exp2f(m - nm);
        float p0[4], p1[4], p2[4], p3[4];
        #pragma unroll
        for (int i = 0; i < 4; ++i) {
            p0[i] = exp2f(a0[i] - nm);
            p1[i] = exp2f(a1[i] - nm);
            p2[i] = exp2f(a2[i] - nm);
            p3[i] = exp2f(a3[i] - nm);
        }
        float ts = ((p0[0] + p0[1]) + (p0[2] + p0[3])) + ((p1[0] + p1[1]) + (p1[2] + p1[3]))
                 + ((p2[0] + p2[1]) + (p2[2] + p2[3])) + ((p3[0] + p3[1]) + (p3[2] + p3[3]));
        ts += __shfl_xor(ts, 16);
        ts += __shfl_xor(ts, 32);
        lsum = lsum * sc + ts;
        m = nm;
        oacc *= sc;

        // P already in PV B-frag order (key permutation in Khl layout)
        union { unsigned u[4]; bf16x8 v; } pf0, pf1;
        pf0.u[0] = pack2(p0[0], p0[1]); pf0.u[1] = pack2(p0[2], p0[3]);
        pf0.u[2] = pack2(p1[0], p1[1]); pf0.u[3] = pack2(p1[2], p1[3]);
        pf1.u[0] = pack2(p2[0], p2[1]); pf1.u[1] = pack2(p2[2], p2[3]);
        pf1.u[2] = pack2(p3[0], p3[1]); pf1.u[3] = pack2(p3[2], p3[3]);
        oacc = __builtin_amdgcn_mfma_f32_16x16x32_bf16(vf0, pf0.v, oacc, 0, 0, 0);
        oacc = __builtin_amdgcn_mfma_f32_16x16x32_bf16(vf1, pf1.v, oacc, 0, 0, 0);

        if (tile + 1 < NTILES) {            // write next tile after compute
            char* nb = (char*)&smem[cur ^ 1][0];
            *(uint4*)(nb + t * 16) = kreg;
            *(uint2*)(nb + 4096 + t * 8) = vreg;
        }
        cur ^= 1;
    }

    const float invl = 1.f / lsum;
    float4 o;
    o.x = oacc[0] * invl; o.y = oacc[1] * invl;
    o.z = oacc[2] * invl; o.w = oacc[3] * invl;
    *(float4*)(Hd + qbase + (size_t)qrow * DK + g * 4) = o;
}

// ---------------- kernel 3: output projection (fp32 VALU, 8 rows/block) -----
constexpr int OUT_ROWS = 8;
__global__ __launch_bounds__(128) void out_kernel(
    const float* __restrict__ Hd, const float* __restrict__ Wout,
    float* __restrict__ out)
{
    const int row0 = blockIdx.x * OUT_ROWS;
    const int b = row0 >> 11, n0 = row0 & (N - 1);
    const int t = threadIdx.x;
    __shared__ float hr[OUT_ROWS][D];
    #pragma unroll
    for (int i = 0; i < 2; ++i) {
        const int f4 = t + i * 128;
        const int r = f4 >> 5, j4 = (f4 & 31) * 4;
        const int head = j4 >> 4, v0 = j4 & 15;
        *(float4*)&hr[r][j4] =
            *(const float4*)&Hd[(((size_t)head * B + b) * N + (n0 + r)) * DK + v0];
    }
    __syncthreads();
    float acc[OUT_ROWS] = {};
    for (int d0 = 0; d0 < D; d0 += 4) {
        float wv[4];
        #pragma unroll
        for (int dd = 0; dd < 4; ++dd) wv[dd] = Wout[(size_t)(d0 + dd) * D + t];
        #pragma unroll
        for (int r = 0; r < OUT_ROWS; ++r) {
            float4 hv = *(const float4*)&hr[r][d0];
            const float* hp = (const float*)&hv;
            #pragma unroll
            for (int dd = 0; dd < 4; ++dd) acc[r] = fmaf(hp[dd], wv[dd], acc[r]);
        }
    }
    #pragma unroll
    for (int r = 0; r < OUT_ROWS; ++r)
        out[(size_t)(row0 + r) * D + t] = acc[r];
}

extern "C" void kernel_launch(void* const* d_in, const int* in_sizes, int n_in,
                              void* d_out, int out_size, void* d_ws, size_t ws_size,
                              hipStream_t stream) {
    const float* h  = (const float*)d_in[0];
    const float* Wq = (const float*)d_in[1];
    const float* Wk = (const float*)d_in[2];
    const float* Wv = (const float*)d_in[3];
    const float* Wo = (const float*)d_in[4];
    float* out = (float*)d_out;

    float* Q = (float*)d_ws;                                  // 4 MB, heads alias
    unsigned short* KV = (unsigned short*)((char*)d_ws + (size_t)4 * 1024 * 1024); // 6 MB

    qkv_kernel<<<B * N / QKV_ROWS, 128, 0, stream>>>(h, Wq, Wk, Wv, Q, KV);
    attn_kernel<<<NH * B * 32, 256, 0, stream>>>(Q, KV, Q);
    out_kernel<<<B * N / OUT_ROWS, 128, 0, stream>>>(Q, Wo, out);
}

// Round 5
// 74.849 us; speedup vs baseline: 5.0223x; 1.3125x over previous
//
#include <hip/hip_runtime.h>

typedef __attribute__((ext_vector_type(4))) float f32x4;
typedef __attribute__((ext_vector_type(8))) short bf16x8;

constexpr int NH = 8, D = 128, DK = 16, B = 4, N = 2048;
constexpr int KTILE = 128;
constexpr int NTILES = N / KTILE;       // 16 key-tiles of 128
constexpr int TILE_SHORTS = 6144;       // 12288 B: 8192 B Khl frag + 4096 B Vt swz
constexpr float QSCALE = 0.36067376022224085f;   // 0.25 * log2(e)

__device__ __forceinline__ unsigned short f2bf(float f) {
    union { float f; unsigned u; } v; v.f = f;
    return (unsigned short)((v.u + 0x7fffu + ((v.u >> 16) & 1u)) >> 16);
}
__device__ __forceinline__ float bf2f(unsigned short h) {
    union { unsigned u; float f; } v; v.u = ((unsigned)h) << 16; return v.f;
}
__device__ __forceinline__ unsigned pack2(float a, float b) {   // bf16 trunc pair
    union { float f; unsigned u; } x, y; x.f = a; y.f = b;
    return (x.u >> 16) | (y.u & 0xFFFF0000u);
}
__device__ __forceinline__ float fexp2(float x) {   // raw v_exp_f32 (FTZ ok: args<=0)
    float r; asm("v_exp_f32 %0, %1" : "=v"(r) : "v"(x)); return r;
}

// ---------------- kernel 1: QKV projection + K/V pre-conversion -------------
// Q fp32 [hb][n][16]. KV per (hb,tile) 12KB record:
//   Khl frag-order (key-permuted rows, hi/lo gsel) bytes [0,8192)
//   V^T bf16 XOR-swizzled (16B granules) bytes [8192,12288)
constexpr int QKV_ROWS = 8;
__global__ __launch_bounds__(128) void qkv_kernel(
    const float* __restrict__ h, const float* __restrict__ Wq,
    const float* __restrict__ Wk, const float* __restrict__ Wv,
    float* __restrict__ Q, unsigned short* __restrict__ KV)
{
    const int row0 = blockIdx.x * QKV_ROWS;
    const int b = row0 >> 11, n0 = row0 & (N - 1);
    const int t = threadIdx.x;
    __shared__ float hs[QKV_ROWS][D];
    #pragma unroll
    for (int i = 0; i < 2; ++i) {
        const int f4 = t + i * 128;
        const int r = f4 >> 5, c4 = (f4 & 31) * 4;
        *(float4*)&hs[r][c4] = *(const float4*)&h[(size_t)(row0 + r) * D + c4];
    }
    __syncthreads();
    const int head = t >> 4, kk = t & 15;
    const float* wq = Wq + head * D * DK + kk;
    const float* wk = Wk + head * D * DK + kk;
    const float* wv = Wv + head * D * DK + kk;
    float aq[QKV_ROWS] = {}, ak[QKV_ROWS] = {}, av[QKV_ROWS] = {};
    for (int d0 = 0; d0 < D; d0 += 4) {
        float wqv[4], wkv[4], wvv[4];
        #pragma unroll
        for (int dd = 0; dd < 4; ++dd) {
            wqv[dd] = wq[(d0 + dd) * DK];
            wkv[dd] = wk[(d0 + dd) * DK];
            wvv[dd] = wv[(d0 + dd) * DK];
        }
        #pragma unroll
        for (int r = 0; r < QKV_ROWS; ++r) {
            float4 hv = *(const float4*)&hs[r][d0];
            const float* hp = (const float*)&hv;
            #pragma unroll
            for (int dd = 0; dd < 4; ++dd) {
                aq[r] = fmaf(hp[dd], wqv[dd], aq[r]);
                ak[r] = fmaf(hp[dd], wkv[dd], ak[r]);
                av[r] = fmaf(hp[dd], wvv[dd], av[r]);
            }
        }
    }
    const int hb = head * B + b;
    unsigned short* kvb = KV + (size_t)hb * NTILES * TILE_SHORTS;
    const int j = kk & 7, gs = kk >> 3;
    #pragma unroll
    for (int r = 0; r < QKV_ROWS; ++r) {
        const int key = n0 + r;
        Q[((size_t)hb * N + key) * DK + kk] = aq[r];
        unsigned short* tb = kvb + (size_t)(key >> 7) * TILE_SHORTS;
        const int rl = key & 127;
        const int kb = rl >> 5, kap = rl & 31;
        const int sub = 2 * kb + ((kap >> 2) & 1);
        const int row16 = 4 * (kap >> 3) + (kap & 3);
        const unsigned short khi = f2bf(ak[r]);
        const unsigned short klo = f2bf(ak[r] - bf2f(khi));
        tb[sub * 512 + (row16 + 16 * gs) * 8 + j] = khi;
        tb[sub * 512 + (row16 + 16 * (2 + gs)) * 8 + j] = klo;
        tb[4096 + kk * 128 + (((rl >> 3) ^ (kk & 7)) * 8) + (rl & 7)] = f2bf(av[r]);
    }
}

// ---------------- kernel 2: flash attention, all-MFMA, in-register P --------
// 4 waves x 16 q-rows; 128-key tiles. Per tile: 8 kf + 4 vf b128 reads,
// 16 QK mfma (hi/lo exact), ONE softmax update (raw v_exp), 4 PV mfma,
// 4 ones-mfma for lsum. Double-buffered reg-staged LDS.
__global__ __launch_bounds__(256, 4) void attn_kernel(
    const float* __restrict__ Q, const unsigned short* __restrict__ KV,
    float* __restrict__ Hd)
{
    const int bid = blockIdx.x;
    const int hb = (bid & 7) * 4 + ((bid >> 3) >> 5);   // XCD swizzle
    const int qt = (bid >> 3) & 31;
    const int t = threadIdx.x, w = t >> 6, l = t & 63;
    const int q16 = l & 15, g = l >> 4;
    const size_t qbase = (size_t)hb * N * DK;
    const char* kvb = (const char*)(KV + (size_t)hb * NTILES * TILE_SHORTS);

    __shared__ unsigned short smem[2][TILE_SHORTS];     // 2 x 12 KB

    const int qrow = qt * 64 + w * 16 + q16;
    bf16x8 qhi, qlo;
    {
        const float* qp = Q + qbase + (size_t)qrow * DK + (g & 1) * 8;
        float4 qa = *(const float4*)qp, qb = *(const float4*)(qp + 4);
        #pragma unroll
        for (int i = 0; i < 8; ++i) {
            const float x = (i < 4 ? ((const float*)&qa)[i] : ((const float*)&qb)[i - 4]) * QSCALE;
            const unsigned short hi = f2bf(x);
            qhi[i] = (short)hi;
            qlo[i] = (short)f2bf(x - bf2f(hi));
        }
    }
    const bf16x8 qf1 = (g < 2) ? qhi : qlo;
    const bf16x8 qf2 = (g < 2) ? qlo : qhi;

    union { unsigned u[4]; bf16x8 v; } ones;
    #pragma unroll
    for (int i = 0; i < 4; ++i) ones.u[i] = 0x3F803F80u;

    f32x4 oacc = {0.f, 0.f, 0.f, 0.f};
    f32x4 lacc = {0.f, 0.f, 0.f, 0.f};
    float m = -3.0e38f;

    // prologue: stage tile 0 (3 x uint4 per thread)
    uint4 s0 = *(const uint4*)(kvb + t * 16);
    uint4 s1 = *(const uint4*)(kvb + 4096 + t * 16);
    uint4 s2 = *(const uint4*)(kvb + 8192 + t * 16);
    *(uint4*)((char*)&smem[0][0] + t * 16) = s0;
    *(uint4*)((char*)&smem[0][0] + 4096 + t * 16) = s1;
    *(uint4*)((char*)&smem[0][0] + 8192 + t * 16) = s2;

    int cur = 0;
    for (int tile = 0; tile < NTILES; ++tile) {
        __syncthreads();
        if (tile + 1 < NTILES) {            // issue next-tile loads early (T14)
            const char* gt = kvb + (size_t)(tile + 1) * 12288;
            s0 = *(const uint4*)(gt + t * 16);
            s1 = *(const uint4*)(gt + 4096 + t * 16);
            s2 = *(const uint4*)(gt + 8192 + t * 16);
        }
        const char* buf = (const char*)&smem[cur][0];

        f32x4 aA[4], aB[4];
        const f32x4 z = {0.f, 0.f, 0.f, 0.f};
        #pragma unroll
        for (int kb = 0; kb < 4; ++kb) {
            bf16x8 kA = *(const bf16x8*)(buf + (2 * kb) * 1024 + l * 16);
            bf16x8 kB = *(const bf16x8*)(buf + (2 * kb + 1) * 1024 + l * 16);
            aA[kb] = __builtin_amdgcn_mfma_f32_16x16x32_bf16(kA, qf1, z, 0, 0, 0);
            aA[kb] = __builtin_amdgcn_mfma_f32_16x16x32_bf16(kA, qf2, aA[kb], 0, 0, 0);
            aB[kb] = __builtin_amdgcn_mfma_f32_16x16x32_bf16(kB, qf1, z, 0, 0, 0);
            aB[kb] = __builtin_amdgcn_mfma_f32_16x16x32_bf16(kB, qf2, aB[kb], 0, 0, 0);
        }

        // one online-softmax update over 128 keys
        float tm = -3.0e38f;
        #pragma unroll
        for (int kb = 0; kb < 4; ++kb) {
            tm = fmaxf(tm, fmaxf(fmaxf(aA[kb][0], aA[kb][1]), fmaxf(aA[kb][2], aA[kb][3])));
            tm = fmaxf(tm, fmaxf(fmaxf(aB[kb][0], aB[kb][1]), fmaxf(aB[kb][2], aB[kb][3])));
        }
        tm = fmaxf(tm, __shfl_xor(tm, 16));
        tm = fmaxf(tm, __shfl_xor(tm, 32));
        const float nm = fmaxf(m, tm);
        const float sc = fexp2(m - nm);
        m = nm;
        #pragma unroll
        for (int kb = 0; kb < 4; ++kb) {
            #pragma unroll
            for (int i = 0; i < 4; ++i) {
                aA[kb][i] = fexp2(aA[kb][i] - nm);
                aB[kb][i] = fexp2(aB[kb][i] - nm);
            }
        }
        oacc *= sc;
        lacc *= sc;
        #pragma unroll
        for (int kb = 0; kb < 4; ++kb) {
            union { unsigned u[4]; bf16x8 v; } pf;
            pf.u[0] = pack2(aA[kb][0], aA[kb][1]);
            pf.u[1] = pack2(aA[kb][2], aA[kb][3]);
            pf.u[2] = pack2(aB[kb][0], aB[kb][1]);
            pf.u[3] = pack2(aB[kb][2], aB[kb][3]);
            bf16x8 vf = *(const bf16x8*)(buf + 8192 + q16 * 256 + (((kb * 4 + g) ^ (q16 & 7)) * 16));
            oacc = __builtin_amdgcn_mfma_f32_16x16x32_bf16(vf, pf.v, oacc, 0, 0, 0);
            lacc = __builtin_amdgcn_mfma_f32_16x16x32_bf16(ones.v, pf.v, lacc, 0, 0, 0);
        }

        if (tile + 1 < NTILES) {            // write next tile after compute
            char* nb = (char*)&smem[cur ^ 1][0];
            *(uint4*)(nb + t * 16) = s0;
            *(uint4*)(nb + 4096 + t * 16) = s1;
            *(uint4*)(nb + 8192 + t * 16) = s2;
        }
        cur ^= 1;
    }

    const float invl = 1.f / lacc[0];      // lacc rows identical = sum_k P[k][q]
    float4 o;
    o.x = oacc[0] * invl; o.y = oacc[1] * invl;
    o.z = oacc[2] * invl; o.w = oacc[3] * invl;
    *(float4*)(Hd + qbase + (size_t)qrow * DK + g * 4) = o;
}

// ---------------- kernel 3: output projection (fp32 VALU, 8 rows/block) -----
constexpr int OUT_ROWS = 8;
__global__ __launch_bounds__(128) void out_kernel(
    const float* __restrict__ Hd, const float* __restrict__ Wout,
    float* __restrict__ out)
{
    const int row0 = blockIdx.x * OUT_ROWS;
    const int b = row0 >> 11, n0 = row0 & (N - 1);
    const int t = threadIdx.x;
    __shared__ float hr[OUT_ROWS][D];
    #pragma unroll
    for (int i = 0; i < 2; ++i) {
        const int f4 = t + i * 128;
        const int r = f4 >> 5, j4 = (f4 & 31) * 4;
        const int head = j4 >> 4, v0 = j4 & 15;
        *(float4*)&hr[r][j4] =
            *(const float4*)&Hd[(((size_t)head * B + b) * N + (n0 + r)) * DK + v0];
    }
    __syncthreads();
    float acc[OUT_ROWS] = {};
    for (int d0 = 0; d0 < D; d0 += 4) {
        float wv[4];
        #pragma unroll
        for (int dd = 0; dd < 4; ++dd) wv[dd] = Wout[(size_t)(d0 + dd) * D + t];
        #pragma unroll
        for (int r = 0; r < OUT_ROWS; ++r) {
            float4 hv = *(const float4*)&hr[r][d0];
            const float* hp = (const float*)&hv;
            #pragma unroll
            for (int dd = 0; dd < 4; ++dd) acc[r] = fmaf(hp[dd], wv[dd], acc[r]);
        }
    }
    #pragma unroll
    for (int r = 0; r < OUT_ROWS; ++r)
        out[(size_t)(row0 + r) * D + t] = acc[r];
}

extern "C" void kernel_launch(void* const* d_in, const int* in_sizes, int n_in,
                              void* d_out, int out_size, void* d_ws, size_t ws_size,
                              hipStream_t stream) {
    const float* h  = (const float*)d_in[0];
    const float* Wq = (const float*)d_in[1];
    const float* Wk = (const float*)d_in[2];
    const float* Wv = (const float*)d_in[3];
    const float* Wo = (const float*)d_in[4];
    float* out = (float*)d_out;

    float* Q = (float*)d_ws;                                  // 4 MB, heads alias
    unsigned short* KV = (unsigned short*)((char*)d_ws + (size_t)4 * 1024 * 1024); // 6 MB

    qkv_kernel<<<B * N / QKV_ROWS, 128, 0, stream>>>(h, Wq, Wk, Wv, Q, KV);
    attn_kernel<<<NH * B * 32, 256, 0, stream>>>(Q, KV, Q);
    out_kernel<<<B * N / OUT_ROWS, 128, 0, stream>>>(Q, Wo, out);
}